// Round 15
// baseline (56.910 us; speedup 1.0000x reference)
//
#include <hip/hip_runtime.h>
#include <math.h>

#define B_SZ   4
#define T_SEQ  4096
#define E_DIM  512
#define H_DIM  64
#define XSTR   520   // LDS x-frag row stride in shorts (64*8 + 8 pad)
#define QSCALE 0.180336878f   // 0.125 * log2(e): softmax scale + exp2-domain fold

typedef float f32x4 __attribute__((ext_vector_type(4)));
typedef short s16x4 __attribute__((ext_vector_type(4)));
typedef short s16x8 __attribute__((ext_vector_type(8)));
typedef unsigned int u32x4 __attribute__((ext_vector_type(4)));

static __device__ __forceinline__ unsigned short f2bf(float f) {
    union { float f; unsigned int u; } c; c.f = f;
    return (unsigned short)((c.u + 0x7fffu + ((c.u >> 16) & 1u)) >> 16);
}

static __device__ __forceinline__ float exp2f_hw(float x) {
    return __builtin_amdgcn_exp2f(x);
}

// round-half-up bf16 pair-pack: returns [bf16(b) : bf16(a)] in one u32.
static __device__ __forceinline__ unsigned int pack_bf16(float a, float b) {
    unsigned int ua = __builtin_bit_cast(unsigned int, a) + 0x8000u;
    unsigned int ub = __builtin_bit_cast(unsigned int, b) + 0x8000u;
    return __builtin_amdgcn_perm(ub, ua, 0x07060302u);
}

// ---------------- W -> bf16 fragment-major layout ----------------
__global__ __launch_bounds__(256) void wconv(
    const float* __restrict__ Wq, const float* __restrict__ Wk, const float* __restrict__ Wv,
    unsigned short* __restrict__ Wf)
{
    const int fid  = blockIdx.x * 256 + threadIdx.x;    // 0..12287
    const int nt   = fid >> 10;
    const int kc32 = (fid >> 6) & 15;
    const int lane = fid & 63;
    const int l15  = lane & 15, g = lane >> 4;
    const int col  = nt * 16 + l15;                     // 0..191
    const int m    = col >> 6, h = col & 63;
    const float* src = (m == 0) ? Wq : (m == 1) ? Wk : Wv;
    const float sc = (m == 0) ? QSCALE : 1.0f;
    const int k0 = kc32 * 32 + 4 * g;
    s16x8 o;
    #pragma unroll
    for (int j = 0; j < 4; ++j) {
        o[j]     = (short)f2bf(src[(k0 + j) * H_DIM + h] * sc);
        o[4 + j] = (short)f2bf(src[(k0 + 16 + j) * H_DIM + h] * sc);
    }
    *(s16x8*)(Wf + (long long)fid * 8) = o;
}

// ---------------- QKV projection via MFMA -> fragment-major Qf/Kf/Vf ----------------
// grid 512 blocks x 256 thr; block = 32 rows (2 qt tiles).
__global__ __launch_bounds__(256) void qkv_mfma(
    const float* __restrict__ x, const unsigned short* __restrict__ Wf,
    const float* __restrict__ bq, const float* __restrict__ bk, const float* __restrict__ bv,
    unsigned short* __restrict__ qf, unsigned short* __restrict__ kf,
    unsigned short* __restrict__ vf)
{
    __shared__ unsigned short Xf[2][16 * XSTR];   // [row-set][kc32][lane][8] + pad
    __shared__ unsigned short Wout[192][36];      // [col][row-in-block(32) + pad]

    const int t = threadIdx.x, wv = t >> 6, l = t & 63, l15 = l & 15, g = l >> 4;
    const long long row0 = (long long)blockIdx.x * 32;

    const float* xbase = x + row0 * E_DIM;
    #pragma unroll
    for (int i = 0; i < 16; ++i) {
        const int n = t + 256 * i;            // 0..4095
        const int r = n >> 7;                 // row 0..31
        const int c = (n & 127) * 4;          // col 0..508
        const f32x4 xv = *(const f32x4*)(xbase + r * E_DIM + c);
        const int rs = r >> 4, rr = r & 15;
        const int kc32 = c >> 5, rem = c & 31;
        const int gg = (rem & 15) >> 2, half = rem >> 4;
        unsigned int* dst = (unsigned int*)&Xf[rs][kc32 * XSTR + (rr + 16 * gg) * 8 + half * 4];
        dst[0] = pack_bf16(xv[0], xv[1]);
        dst[1] = pack_bf16(xv[2], xv[3]);
    }
    __syncthreads();

    f32x4 acc[2][3];
    #pragma unroll
    for (int rs = 0; rs < 2; ++rs)
        #pragma unroll
        for (int i = 0; i < 3; ++i) acc[rs][i] = (f32x4){0.f, 0.f, 0.f, 0.f};

    #pragma unroll
    for (int kc32 = 0; kc32 < 16; ++kc32) {
        const s16x8 xf0 = *(const s16x8*)&Xf[0][kc32 * XSTR + l * 8];
        const s16x8 xf1 = *(const s16x8*)&Xf[1][kc32 * XSTR + l * 8];
        #pragma unroll
        for (int i = 0; i < 3; ++i) {
            const int nt = wv + 4 * i;
            const s16x8 wf = *(const s16x8*)(Wf + (long long)((nt * 16 + kc32) * 64 + l) * 8);
            acc[0][i] = __builtin_amdgcn_mfma_f32_16x16x32_bf16(wf, xf0, acc[0][i], 0, 0, 0);
            acc[1][i] = __builtin_amdgcn_mfma_f32_16x16x32_bf16(wf, xf1, acc[1][i], 0, 0, 0);
        }
    }

    #pragma unroll
    for (int i = 0; i < 3; ++i) {
        const int nt = wv + 4 * i;
        const float* bsrc = (i == 0) ? bq : (i == 1) ? bk : bv;
        const float bscale = (i == 0) ? QSCALE : 1.0f;
        const f32x4 bb = *(const f32x4*)(bsrc + wv * 16 + 4 * g);
        #pragma unroll
        for (int rs = 0; rs < 2; ++rs)
            #pragma unroll
            for (int r = 0; r < 4; ++r)
                Wout[nt * 16 + 4 * g + r][16 * rs + l15] = f2bf(acc[rs][i][r] + bb[r] * bscale);
    }
    __syncthreads();

    #pragma unroll
    for (int rt = 0; rt < 2; ++rt) {
        const long long qt = (long long)blockIdx.x * 2 + rt;

        if (t < 128) {
            const int hc = t >> 6, ll = t & 63, p15 = ll & 15, pg = (ll >> 4);
            s16x8 o;
            #pragma unroll
            for (int j = 0; j < 4; ++j) {
                o[j]     = (short)Wout[32 * hc + 4 * pg + j][16 * rt + p15];
                o[4 + j] = (short)Wout[32 * hc + 16 + 4 * pg + j][16 * rt + p15];
            }
            *(s16x8*)(qf + qt * 1024 + hc * 512 + ll * 8) = o;
        } else {
            const int tt = t - 128, half = tt >> 6, ll = tt & 63, p15 = ll & 15, pg = (ll >> 4);
            s16x8 o;
            #pragma unroll
            for (int j = 0; j < 4; ++j) {
                o[j]     = (short)Wout[64 + 32 * half + 4 * pg + j][16 * rt + p15];
                o[4 + j] = (short)Wout[64 + 32 * half + 16 + 4 * pg + j][16 * rt + p15];
            }
            *(s16x8*)(kf + qt * 1024 + half * 512 + ll * 8) = o;
        }

        {
            const int hc = t >> 6, ll = t & 63, p15 = ll & 15, pg = (ll >> 4);
            const long long ktg = qt >> 2;
            const int half = (int)((qt >> 1) & 1), pi = (int)(qt & 1);
            s16x4 o;
            #pragma unroll
            for (int j = 0; j < 4; ++j)
                o[j] = (short)Wout[128 + hc * 16 + p15][16 * rt + 4 * pg + j];
            *(s16x4*)(vf + ktg * 4096 + hc * 1024 + half * 512 + ll * 8 + pi * 4) = o;
        }
    }
}

// ---------------- causal flash attention: 64-row blocks, LDS-shared K/V ----------------
// grid 256 blocks x 8 waves = 2 q-groups (32 rows each) x 4-way split-K.
// Each k-tile staged into LDS ONCE per block (qg0 waves stage K-half, qg1 V-half;
// T14 split: loads at step top, ds_write after PV) and consumed by BOTH q-groups
// -> L2 traffic halves vs r13 (266 -> 133 MB). Double-buffered slots, one
// __syncthreads per step. Per-wave registers identical to r13 (~165 peak, no
// spill at (512,1)); r14's failure was the 4-subtile-in-registers variant.
__global__ __launch_bounds__(512, 1) void attn(
    const unsigned short* __restrict__ qf,
    const unsigned short* __restrict__ kf,
    const unsigned short* __restrict__ vf,
    float* __restrict__ out)
{
    __shared__ __align__(16) char raw[131072];   // 8 slots x 16KB (2 bufs x 4 tiles); aliased for merge
    __shared__ float msh[2][4][32];
    __shared__ float lsh[2][4][32];

    const int t = threadIdx.x, wv = t >> 6, l = t & 63, l15 = l & 15, g = l >> 4;
    const int qg = wv >> 2, j = wv & 3;

    const int bid = blockIdx.x;
    const int xcd = bid & 7;
    const int b   = xcd >> 1;
    const int u   = (bid >> 3) * 2 + (xcd & 1);   // 0..63
    const int qi  = 63 - u;                       // 64-row tile, longest-first per XCD
    const int q0  = qi * 64;
    const int adiag = qi;

    const unsigned short* kfb = kf + (long long)b * 64 * 4096;
    const unsigned short* vfb = vf + (long long)b * 64 * 4096;
    const unsigned short* sfb = qg ? vfb : kfb;   // this wave's staging source

    // Q fragments: rows q0 + 32*qg + 16*s + l15  (qt = qi*4 + qg*2 + s)
    s16x8 Qf[2][2];
    #pragma unroll
    for (int s = 0; s < 2; ++s) {
        const unsigned short* qp = qf + ((long long)b * 256 + qi * 4 + qg * 2 + s) * 1024 + l * 8;
        Qf[s][0] = *(const s16x8*)qp;
        Qf[s][1] = *(const s16x8*)(qp + 512);
    }

    f32x4 O[2][4];
    #pragma unroll
    for (int s = 0; s < 2; ++s)
        #pragma unroll
        for (int hc = 0; hc < 4; ++hc) O[s][hc] = (f32x4){0.f, 0.f, 0.f, 0.f};
    float m[2]   = {-INFINITY, -INFINITY};
    float lsm[2] = {0.f, 0.f};

    // ---- prologue: stage tiles {0..3} (clipped) into buf 0 ----
    if (j <= adiag) {
        const unsigned short* src = sfb + (long long)j * 4096 + l * 8;
        char* dst = raw + j * 16384 + qg * 8192 + l * 16;
        #pragma unroll
        for (int c = 0; c < 8; ++c)
            *(u32x4*)(dst + c * 1024) = *(const u32x4*)(src + c * 512);
    }
    __syncthreads();

    const int N = adiag / 4 + 1;
    for (int n = 0; n < N; ++n) {
        const int cur = n & 1;

        // ---- stage-load for step n+1 (T14: issue early, write late) ----
        u32x4 stg[8];
        const int kt2 = 4 * (n + 1) + j;
        const bool do_stage = (kt2 <= adiag);
        if (do_stage) {
            const unsigned short* src = sfb + (long long)kt2 * 4096 + l * 8;
            #pragma unroll
            for (int c = 0; c < 8; ++c) stg[c] = *(const u32x4*)(src + c * 512);
        }

        const int kt = 4 * n + j;
        if (kt <= adiag) {
            const char* slot = raw + ((cur << 2) | j) * 16384 + l * 16;
            const int ktb = kt * 64;
            const f32x4 z = {0.f, 0.f, 0.f, 0.f};

            s16x8 Ka[4], Kc[4];
            #pragma unroll
            for (int ks = 0; ks < 4; ++ks) {
                Ka[ks] = *(const s16x8*)(slot + ks * 2048);
                Kc[ks] = *(const s16x8*)(slot + ks * 2048 + 1024);
            }

            // ---- QK^T: 16 MFMAs ----
            f32x4 S[2][4];
            __builtin_amdgcn_s_setprio(1);
            #pragma unroll
            for (int ks = 0; ks < 4; ++ks) {
                #pragma unroll
                for (int s = 0; s < 2; ++s) {
                    f32x4 s0 = __builtin_amdgcn_mfma_f32_16x16x32_bf16(Ka[ks], Qf[s][0], z, 0, 0, 0);
                    S[s][ks] = __builtin_amdgcn_mfma_f32_16x16x32_bf16(Kc[ks], Qf[s][1], s0, 0, 0, 0);
                }
            }
            __builtin_amdgcn_s_setprio(0);

            s16x8 Va[4], Vc[4];
            #pragma unroll
            for (int hc = 0; hc < 4; ++hc) {
                Va[hc] = *(const s16x8*)(slot + 8192 + hc * 2048);
                Vc[hc] = *(const s16x8*)(slot + 8192 + hc * 2048 + 1024);
            }

            if (kt == adiag) {   // causal mask, diagonal tile only
                #pragma unroll
                for (int s = 0; s < 2; ++s) {
                    const int qg_row = q0 + 32 * qg + 16 * s + l15;
                    #pragma unroll
                    for (int ks = 0; ks < 4; ++ks)
                        #pragma unroll
                        for (int r = 0; r < 4; ++r) {
                            const int key = ktb + 16 * ks + 4 * g + r;
                            S[s][ks][r] = (key > qg_row) ? -INFINITY : S[s][ks][r];
                        }
                }
            }

            // ---- online softmax (exp2 domain, defer-max, per-lane l-partials) ----
            s16x8 Pf[2][2];
            #pragma unroll
            for (int s = 0; s < 2; ++s) {
                float tm = S[s][0][0];
                #pragma unroll
                for (int ks = 0; ks < 4; ++ks)
                    #pragma unroll
                    for (int r = 0; r < 4; ++r) tm = fmaxf(tm, S[s][ks][r]);

                if (!__all(tm - m[s] <= 8.f)) {
                    float tr = fmaxf(tm, __shfl_xor(tm, 16));
                    tr = fmaxf(tr, __shfl_xor(tr, 32));
                    const float mn = fmaxf(m[s], tr);
                    const float alpha = exp2f_hw(m[s] - mn);
                    lsm[s] *= alpha;
                    #pragma unroll
                    for (int hc = 0; hc < 4; ++hc) O[s][hc] *= alpha;
                    m[s] = mn;
                }

                float ps = 0.f;
                #pragma unroll
                for (int ks = 0; ks < 4; ++ks)
                    #pragma unroll
                    for (int r = 0; r < 4; ++r) {
                        const float pp = exp2f_hw(S[s][ks][r] - m[s]);
                        S[s][ks][r] = pp;
                        ps += pp;
                    }
                lsm[s] += ps;

                #pragma unroll
                for (int kc = 0; kc < 2; ++kc) {
                    u32x4 w;
                    #pragma unroll
                    for (int i = 0; i < 4; ++i)
                        w[i] = pack_bf16(S[s][2 * kc + (i >> 1)][2 * (i & 1)],
                                         S[s][2 * kc + (i >> 1)][2 * (i & 1) + 1]);
                    Pf[s][kc] = __builtin_bit_cast(s16x8, w);
                }
            }

            // ---- PV: 16 MFMAs ----
            __builtin_amdgcn_s_setprio(1);
            #pragma unroll
            for (int hc = 0; hc < 4; ++hc) {
                #pragma unroll
                for (int s = 0; s < 2; ++s) {
                    O[s][hc] = __builtin_amdgcn_mfma_f32_16x16x32_bf16(Va[hc], Pf[s][0], O[s][hc], 0, 0, 0);
                    O[s][hc] = __builtin_amdgcn_mfma_f32_16x16x32_bf16(Vc[hc], Pf[s][1], O[s][hc], 0, 0, 0);
                }
            }
            __builtin_amdgcn_s_setprio(0);
        }

        // ---- stage-write for step n+1 (into the idle buffer) ----
        if (do_stage) {
            char* dst = raw + (((cur ^ 1) << 2) | j) * 16384 + qg * 8192 + l * 16;
            #pragma unroll
            for (int c = 0; c < 8; ++c) *(u32x4*)(dst + c * 1024) = stg[c];
        }
        __syncthreads();   // swap double-buffer: drains ds_writes + protects reads
    }

    // ---- one-time cross-lane l reduction ----
    #pragma unroll
    for (int s = 0; s < 2; ++s) {
        lsm[s] += __shfl_xor(lsm[s], 16);
        lsm[s] += __shfl_xor(lsm[s], 32);
    }

    // ---- 4-way split-K merge per q-group (alias staging LDS; loop barrier drained reads) ----
    float* OshG = (float*)(raw + qg * 36864);    // [w][h][row+pad] = [4][64][33]
    #pragma unroll
    for (int s = 0; s < 2; ++s)
        #pragma unroll
        for (int hc = 0; hc < 4; ++hc)
            #pragma unroll
            for (int r = 0; r < 4; ++r)
                OshG[j * 2112 + (hc * 16 + 4 * g + r) * 33 + 16 * s + l15] = O[s][hc][r];
    if (g == 0) {
        msh[qg][j][l15]      = m[0];
        msh[qg][j][16 + l15] = m[1];
        lsh[qg][j][l15]      = lsm[0];
        lsh[qg][j][16 + l15] = lsm[1];
    }
    __syncthreads();

    const int qg2 = t >> 8, tt = t & 255;
    const int rl = tt >> 3;          // 0..31 row within q-group
    const int h0 = (tt & 7) * 8;     // 8 cols per thread
    const float* OshR = (const float*)(raw + qg2 * 36864);

    float mstar = msh[qg2][0][rl];
    #pragma unroll
    for (int w = 1; w < 4; ++w) mstar = fmaxf(mstar, msh[qg2][w][rl]);
    float fw[4], lstar = 0.f;
    #pragma unroll
    for (int w = 0; w < 4; ++w) {
        fw[w] = exp2f_hw(msh[qg2][w][rl] - mstar);
        lstar += lsh[qg2][w][rl] * fw[w];
    }
    const float inv = 1.f / lstar;

    f32x4 o0, o1;
    #pragma unroll
    for (int jj = 0; jj < 4; ++jj) {
        float a0 = 0.f, a1 = 0.f;
        #pragma unroll
        for (int w = 0; w < 4; ++w) {
            a0 += OshR[w * 2112 + (h0 + jj) * 33 + rl] * fw[w];
            a1 += OshR[w * 2112 + (h0 + 4 + jj) * 33 + rl] * fw[w];
        }
        o0[jj] = a0 * inv;
        o1[jj] = a1 * inv;
    }
    float* op = out + ((long long)b * T_SEQ + q0 + qg2 * 32 + rl) * H_DIM + h0;
    *(f32x4*)op = o0;
    *(f32x4*)(op + 4) = o1;
}

extern "C" void kernel_launch(void* const* d_in, const int* in_sizes, int n_in,
                              void* d_out, int out_size, void* d_ws, size_t ws_size,
                              hipStream_t stream) {
    const float* x  = (const float*)d_in[0];
    const float* Wq = (const float*)d_in[1];
    const float* bq = (const float*)d_in[2];
    const float* Wk = (const float*)d_in[3];
    const float* bk = (const float*)d_in[4];
    const float* Wv = (const float*)d_in[5];
    const float* bv = (const float*)d_in[6];

    const long long rows = (long long)B_SZ * T_SEQ;          // 16384
    unsigned short* qfb = (unsigned short*)d_ws;             // 1024 qt x 1024 shorts
    unsigned short* kfb = qfb + rows * H_DIM;
    unsigned short* vfb = kfb + rows * H_DIM;
    unsigned short* Wfb = vfb + rows * H_DIM;                // 12288 frags x 16B

    wconv<<<dim3(48), dim3(256), 0, stream>>>(Wq, Wk, Wv, Wfb);
    qkv_mfma<<<dim3(rows / 32), dim3(256), 0, stream>>>(x, Wfb, bq, bk, bv, qfb, kfb, vfb);
    attn<<<dim3(B_SZ * 64), dim3(512), 0, stream>>>(qfb, kfb, vfb, (float*)d_out);
}

// Round 16
// 41.497 us; speedup vs baseline: 1.3714x; 1.3714x over previous
//
#include <hip/hip_runtime.h>
#include <math.h>

#define B_SZ   4
#define T_SEQ  4096
#define E_DIM  512
#define H_DIM  64
#define AW     8     // waves per attn block (split-K factor)
#define XSTR   520   // LDS x-frag row stride in shorts (64*8 + 8 pad)
#define QSCALE 0.180336878f   // 0.125 * log2(e): softmax scale + exp2-domain fold

typedef float f32x4 __attribute__((ext_vector_type(4)));
typedef short s16x4 __attribute__((ext_vector_type(4)));
typedef short s16x8 __attribute__((ext_vector_type(8)));
typedef unsigned int u32x4 __attribute__((ext_vector_type(4)));

static __device__ __forceinline__ unsigned short f2bf(float f) {
    union { float f; unsigned int u; } c; c.f = f;
    return (unsigned short)((c.u + 0x7fffu + ((c.u >> 16) & 1u)) >> 16);
}

static __device__ __forceinline__ float exp2f_hw(float x) {
    return __builtin_amdgcn_exp2f(x);
}

// round-half-up bf16 pair-pack: returns [bf16(b) : bf16(a)] in one u32.
static __device__ __forceinline__ unsigned int pack_bf16(float a, float b) {
    unsigned int ua = __builtin_bit_cast(unsigned int, a) + 0x8000u;
    unsigned int ub = __builtin_bit_cast(unsigned int, b) + 0x8000u;
    return __builtin_amdgcn_perm(ub, ua, 0x07060302u);
}

// ---------------- W -> bf16 fragment-major layout ----------------
__global__ __launch_bounds__(256) void wconv(
    const float* __restrict__ Wq, const float* __restrict__ Wk, const float* __restrict__ Wv,
    unsigned short* __restrict__ Wf)
{
    const int fid  = blockIdx.x * 256 + threadIdx.x;    // 0..12287
    const int nt   = fid >> 10;
    const int kc32 = (fid >> 6) & 15;
    const int lane = fid & 63;
    const int l15  = lane & 15, g = lane >> 4;
    const int col  = nt * 16 + l15;                     // 0..191
    const int m    = col >> 6, h = col & 63;
    const float* src = (m == 0) ? Wq : (m == 1) ? Wk : Wv;
    const float sc = (m == 0) ? QSCALE : 1.0f;
    const int k0 = kc32 * 32 + 4 * g;
    s16x8 o;
    #pragma unroll
    for (int j = 0; j < 4; ++j) {
        o[j]     = (short)f2bf(src[(k0 + j) * H_DIM + h] * sc);
        o[4 + j] = (short)f2bf(src[(k0 + 16 + j) * H_DIM + h] * sc);
    }
    *(s16x8*)(Wf + (long long)fid * 8) = o;
}

// ---------------- QKV projection via MFMA -> fragment-major Qf/Kf/Vf ----------------
// grid 256 blocks x 256 thr; block = 64 rows (4 qt tiles, 4 row-sets).
// Rationale (r16): qkv was ~13 µs vs ~6 µs HBM floor. 64-row blocks (a) issue
// 32 staged f32x4 loads/thread up-front (64 KB/CU in flight -> HBM BW saturation),
// (b) reuse each Wf fragment for FOUR MFMAs (Wf L2 traffic 98 -> 49 MB).
__global__ __launch_bounds__(256) void qkv_mfma(
    const float* __restrict__ x, const unsigned short* __restrict__ Wf,
    const float* __restrict__ bq, const float* __restrict__ bk, const float* __restrict__ bv,
    unsigned short* __restrict__ qf, unsigned short* __restrict__ kf,
    unsigned short* __restrict__ vf)
{
    __shared__ unsigned short Xf[4][16 * XSTR];   // [row-set][kc32][lane][8] + pad (66.5 KB)
    __shared__ unsigned short Wout[192][68];      // [col][row-in-block(64) + pad] (26 KB)

    const int t = threadIdx.x, wv = t >> 6, l = t & 63, l15 = l & 15, g = l >> 4;
    const long long row0 = (long long)blockIdx.x * 64;

    // ---- stage x (64 rows x 512) -> bf16 fragment layout in LDS ----
    const float* xbase = x + row0 * E_DIM;
    #pragma unroll
    for (int i = 0; i < 32; ++i) {
        const int n = t + 256 * i;            // 0..8191
        const int r = n >> 7;                 // row 0..63
        const int c = (n & 127) * 4;          // col 0..508
        const f32x4 xv = *(const f32x4*)(xbase + r * E_DIM + c);
        const int rs = r >> 4, rr = r & 15;
        const int kc32 = c >> 5, rem = c & 31;
        const int gg = (rem & 15) >> 2, half = rem >> 4;
        unsigned int* dst = (unsigned int*)&Xf[rs][kc32 * XSTR + (rr + 16 * gg) * 8 + half * 4];
        dst[0] = pack_bf16(xv[0], xv[1]);
        dst[1] = pack_bf16(xv[2], xv[3]);
    }
    __syncthreads();

    f32x4 acc[4][3];
    #pragma unroll
    for (int rs = 0; rs < 4; ++rs)
        #pragma unroll
        for (int i = 0; i < 3; ++i) acc[rs][i] = (f32x4){0.f, 0.f, 0.f, 0.f};

    #pragma unroll
    for (int kc32 = 0; kc32 < 16; ++kc32) {
        s16x8 xfv[4];
        #pragma unroll
        for (int rs = 0; rs < 4; ++rs)
            xfv[rs] = *(const s16x8*)&Xf[rs][kc32 * XSTR + l * 8];
        #pragma unroll
        for (int i = 0; i < 3; ++i) {
            const int nt = wv + 4 * i;
            const s16x8 wf = *(const s16x8*)(Wf + (long long)((nt * 16 + kc32) * 64 + l) * 8);
            #pragma unroll
            for (int rs = 0; rs < 4; ++rs)
                acc[rs][i] = __builtin_amdgcn_mfma_f32_16x16x32_bf16(wf, xfv[rs], acc[rs][i], 0, 0, 0);
        }
    }

    #pragma unroll
    for (int i = 0; i < 3; ++i) {
        const int nt = wv + 4 * i;
        const float* bsrc = (i == 0) ? bq : (i == 1) ? bk : bv;
        const float bscale = (i == 0) ? QSCALE : 1.0f;
        const f32x4 bb = *(const f32x4*)(bsrc + wv * 16 + 4 * g);
        #pragma unroll
        for (int rs = 0; rs < 4; ++rs)
            #pragma unroll
            for (int r = 0; r < 4; ++r)
                Wout[nt * 16 + 4 * g + r][16 * rs + l15] = f2bf(acc[rs][i][r] + bb[r] * bscale);
    }
    __syncthreads();

    #pragma unroll
    for (int rt = 0; rt < 4; ++rt) {
        const long long qt = (long long)blockIdx.x * 4 + rt;

        // ---- Qf (t<128) / Kf (t>=128): 16B per lane, fully coalesced ----
        if (t < 128) {
            const int hc = t >> 6, ll = t & 63, p15 = ll & 15, pg = (ll >> 4);
            s16x8 o;
            #pragma unroll
            for (int j = 0; j < 4; ++j) {
                o[j]     = (short)Wout[32 * hc + 4 * pg + j][16 * rt + p15];
                o[4 + j] = (short)Wout[32 * hc + 16 + 4 * pg + j][16 * rt + p15];
            }
            *(s16x8*)(qf + qt * 1024 + hc * 512 + ll * 8) = o;
        } else {
            const int tt = t - 128, half = tt >> 6, ll = tt & 63, p15 = ll & 15, pg = (ll >> 4);
            s16x8 o;
            #pragma unroll
            for (int j = 0; j < 4; ++j) {
                o[j]     = (short)Wout[64 + 32 * half + 4 * pg + j][16 * rt + p15];
                o[4 + j] = (short)Wout[64 + 32 * half + 16 + 4 * pg + j][16 * rt + p15];
            }
            *(s16x8*)(kf + qt * 1024 + half * 512 + ll * 8) = o;
        }

        // ---- Vf: piece (qt&1) of half ((qt>>1)&1) for 4 hc frags ----
        {
            const int hc = t >> 6, ll = t & 63, p15 = ll & 15, pg = (ll >> 4);
            const long long ktg = qt >> 2;
            const int half = (int)((qt >> 1) & 1), pi = (int)(qt & 1);
            s16x4 o;
            #pragma unroll
            for (int j = 0; j < 4; ++j)
                o[j] = (short)Wout[128 + hc * 16 + p15][16 * rt + 4 * pg + j];
            *(s16x4*)(vf + ktg * 4096 + hc * 1024 + half * 512 + ll * 8 + pi * 4) = o;
        }
    }
}

// ---------------- causal flash attention: 512 blocks (one 32-row q-tile each) ----------------
// Reverted verbatim to round 13 (best measured: 41.8 µs total). 512 blocks x 8
// waves -> 2 resident blocks/CU; per-lane l-partials; shfls only in rescale branch.
__global__ __launch_bounds__(512, 2) void attn(
    const unsigned short* __restrict__ qf,
    const unsigned short* __restrict__ kf,
    const unsigned short* __restrict__ vf,
    float* __restrict__ out)
{
    __shared__ float Osh[AW][64][33];
    __shared__ float msh[AW][32];
    __shared__ float lsh[AW][32];

    const int t = threadIdx.x, wv = t >> 6, l = t & 63, l15 = l & 15, g = l >> 4;

    const int bid = blockIdx.x;
    const int xcd = bid & 7;
    const int b   = xcd >> 1;
    const int u   = (bid >> 3) * 2 + (xcd & 1);   // 0..127
    const int qi  = 127 - u;                      // longest-first per XCD stream
    const int q0  = qi * 32;
    const int adiag = (q0 + 31) >> 6;

    const unsigned short* kfb = kf + (long long)b * 64 * 4096 + l * 8;
    const unsigned short* vfb = vf + (long long)b * 64 * 4096 + l * 8;

    s16x8 Qf[2][2];
    #pragma unroll
    for (int s = 0; s < 2; ++s) {
        const unsigned short* qp = qf + ((long long)b * 256 + qi * 2 + s) * 1024 + l * 8;
        Qf[s][0] = *(const s16x8*)qp;
        Qf[s][1] = *(const s16x8*)(qp + 512);
    }

    f32x4 O[2][4];
    #pragma unroll
    for (int s = 0; s < 2; ++s)
        #pragma unroll
        for (int hc = 0; hc < 4; ++hc) O[s][hc] = (f32x4){0.f, 0.f, 0.f, 0.f};
    float m[2]   = {-INFINITY, -INFINITY};
    float lsm[2] = {0.f, 0.f};     // per-lane partial sums (reduced across g at end)

    s16x8 Ka[4], Kc[4];
    #define LOAD_K(KT, A, C)                                              \
        {                                                                 \
            const unsigned short* p_ = kfb + (long long)(KT) * 4096;      \
            _Pragma("unroll")                                             \
            for (int ks = 0; ks < 4; ++ks) {                              \
                (A)[ks] = *(const s16x8*)(p_ + ks * 1024);                \
                (C)[ks] = *(const s16x8*)(p_ + ks * 1024 + 512);          \
            }                                                             \
        }

    if (wv <= adiag) LOAD_K(wv, Ka, Kc);

    for (int kt = wv; kt <= adiag; kt += AW) {
        const int ktb = kt * 64;
        const f32x4 z = {0.f, 0.f, 0.f, 0.f};

        // ---- QK^T: 16 MFMAs ----
        f32x4 S[2][4];
        __builtin_amdgcn_s_setprio(1);
        #pragma unroll
        for (int ks = 0; ks < 4; ++ks) {
            #pragma unroll
            for (int s = 0; s < 2; ++s) {
                f32x4 s0 = __builtin_amdgcn_mfma_f32_16x16x32_bf16(Ka[ks], Qf[s][0], z, 0, 0, 0);
                S[s][ks] = __builtin_amdgcn_mfma_f32_16x16x32_bf16(Kc[ks], Qf[s][1], s0, 0, 0, 0);
            }
        }
        __builtin_amdgcn_s_setprio(0);

        // ---- V frags (independent of softmax -> issue early) ----
        s16x8 Va[4], Vc[4];
        {
            const unsigned short* pv = vfb + (long long)kt * 4096;
            #pragma unroll
            for (int hc = 0; hc < 4; ++hc) {
                Va[hc] = *(const s16x8*)(pv + hc * 1024);
                Vc[hc] = *(const s16x8*)(pv + hc * 1024 + 512);
            }
        }

        // ---- prefetch next K tile (wave-uniform branch; skip on tail) ----
        s16x8 Kna[4], Knc[4];
        const int ktn = kt + AW;
        if (ktn <= adiag) LOAD_K(ktn, Kna, Knc);

        if (kt == adiag) {   // causal mask, diagonal tile only
            #pragma unroll
            for (int s = 0; s < 2; ++s) {
                const int qg = q0 + 16 * s + l15;
                #pragma unroll
                for (int ks = 0; ks < 4; ++ks)
                    #pragma unroll
                    for (int r = 0; r < 4; ++r) {
                        const int key = ktb + 16 * ks + 4 * g + r;
                        S[s][ks][r] = (key > qg) ? -INFINITY : S[s][ks][r];
                    }
            }
        }

        // ---- online softmax: per-lane tm vote; shfls only in rescale branch ----
        s16x8 Pf[2][2];
        #pragma unroll
        for (int s = 0; s < 2; ++s) {
            float tm = S[s][0][0];
            #pragma unroll
            for (int ks = 0; ks < 4; ++ks)
                #pragma unroll
                for (int r = 0; r < 4; ++r) tm = fmaxf(tm, S[s][ks][r]);

            if (!__all(tm - m[s] <= 8.f)) {    // rare: real max growth
                float tr = fmaxf(tm, __shfl_xor(tm, 16));
                tr = fmaxf(tr, __shfl_xor(tr, 32));
                const float mn = fmaxf(m[s], tr);
                const float alpha = exp2f_hw(m[s] - mn);
                lsm[s] *= alpha;
                #pragma unroll
                for (int hc = 0; hc < 4; ++hc) O[s][hc] *= alpha;
                m[s] = mn;
            }

            float ps = 0.f;
            #pragma unroll
            for (int ks = 0; ks < 4; ++ks)
                #pragma unroll
                for (int r = 0; r < 4; ++r) {
                    const float pp = exp2f_hw(S[s][ks][r] - m[s]);
                    S[s][ks][r] = pp;
                    ps += pp;
                }
            lsm[s] += ps;    // per-lane partial; no cross-lane reduce here

            #pragma unroll
            for (int kc = 0; kc < 2; ++kc) {
                u32x4 w;
                #pragma unroll
                for (int i = 0; i < 4; ++i)
                    w[i] = pack_bf16(S[s][2 * kc + (i >> 1)][2 * (i & 1)],
                                     S[s][2 * kc + (i >> 1)][2 * (i & 1) + 1]);
                Pf[s][kc] = __builtin_bit_cast(s16x8, w);
            }
        }

        // ---- PV: 16 MFMAs ----
        __builtin_amdgcn_s_setprio(1);
        #pragma unroll
        for (int hc = 0; hc < 4; ++hc) {
            #pragma unroll
            for (int s = 0; s < 2; ++s) {
                O[s][hc] = __builtin_amdgcn_mfma_f32_16x16x32_bf16(Va[hc], Pf[s][0], O[s][hc], 0, 0, 0);
                O[s][hc] = __builtin_amdgcn_mfma_f32_16x16x32_bf16(Vc[hc], Pf[s][1], O[s][hc], 0, 0, 0);
            }
        }
        __builtin_amdgcn_s_setprio(0);

        #pragma unroll
        for (int ks = 0; ks < 4; ++ks) { Ka[ks] = Kna[ks]; Kc[ks] = Knc[ks]; }
    }
    #undef LOAD_K

    // ---- one-time cross-lane l reduction (was per-iteration) ----
    #pragma unroll
    for (int s = 0; s < 2; ++s) {
        lsm[s] += __shfl_xor(lsm[s], 16);
        lsm[s] += __shfl_xor(lsm[s], 32);
    }

    // ---- split-K merge across 8 waves (m in log2 domain) ----
    #pragma unroll
    for (int s = 0; s < 2; ++s)
        #pragma unroll
        for (int hc = 0; hc < 4; ++hc)
            #pragma unroll
            for (int r = 0; r < 4; ++r)
                Osh[wv][hc * 16 + 4 * g + r][16 * s + l15] = O[s][hc][r];
    if (g == 0) {
        msh[wv][l15]      = m[0];
        msh[wv][16 + l15] = m[1];
        lsh[wv][l15]      = lsm[0];
        lsh[wv][16 + l15] = lsm[1];
    }
    __syncthreads();

    const int rl = t >> 4;          // 0..31 local q-row
    const int h0 = (t & 15) * 4;
    float mstar = msh[0][rl];
    #pragma unroll
    for (int w = 1; w < AW; ++w) mstar = fmaxf(mstar, msh[w][rl]);
    float fw[AW], lstar = 0.f;
    #pragma unroll
    for (int w = 0; w < AW; ++w) {
        fw[w] = exp2f_hw(msh[w][rl] - mstar);
        lstar += lsh[w][rl] * fw[w];
    }
    const float inv = 1.f / lstar;

    f32x4 o0;
    #pragma unroll
    for (int j = 0; j < 4; ++j) {
        float a0 = 0.f;
        #pragma unroll
        for (int w = 0; w < AW; ++w) a0 += Osh[w][h0 + j][rl] * fw[w];
        o0[j] = a0 * inv;
    }
    *(f32x4*)(out + ((long long)b * T_SEQ + q0 + rl) * H_DIM + h0) = o0;
}

extern "C" void kernel_launch(void* const* d_in, const int* in_sizes, int n_in,
                              void* d_out, int out_size, void* d_ws, size_t ws_size,
                              hipStream_t stream) {
    const float* x  = (const float*)d_in[0];
    const float* Wq = (const float*)d_in[1];
    const float* bq = (const float*)d_in[2];
    const float* Wk = (const float*)d_in[3];
    const float* bk = (const float*)d_in[4];
    const float* Wv = (const float*)d_in[5];
    const float* bv = (const float*)d_in[6];

    const long long rows = (long long)B_SZ * T_SEQ;          // 16384
    unsigned short* qfb = (unsigned short*)d_ws;             // 1024 qt x 1024 shorts
    unsigned short* kfb = qfb + rows * H_DIM;
    unsigned short* vfb = kfb + rows * H_DIM;
    unsigned short* Wfb = vfb + rows * H_DIM;                // 12288 frags x 16B

    wconv<<<dim3(48), dim3(256), 0, stream>>>(Wq, Wk, Wv, Wfb);
    qkv_mfma<<<dim3(rows / 64), dim3(256), 0, stream>>>(x, Wfb, bq, bk, bv, qfb, kfb, vfb);
    attn<<<dim3(B_SZ * 128), dim3(512), 0, stream>>>(qfb, kfb, vfb, (float*)d_out);
}